// Round 4
// baseline (138.242 us; speedup 1.0000x reference)
//
#include <hip/hip_runtime.h>

// Problem constants (from reference setup_inputs)
#define BATCH 256
#define SEQ   2048
#define VOCAB 128000
#define HALF  64000              // vocab slots owned per block
#define HSLOT 4096               // hash slots; distinct tokens/row <= 2048 < 4096

typedef float v4f __attribute__((ext_vector_type(4)));
typedef int   v4i __attribute__((ext_vector_type(4)));
typedef float v2f __attribute__((ext_vector_type(2)));
typedef int   v2i __attribute__((ext_vector_type(2)));

// lgkmcnt-only barrier (orders LDS without draining outstanding global stores)
#define LBAR() do { asm volatile("s_waitcnt lgkmcnt(0)" ::: "memory"); \
                    __builtin_amdgcn_s_barrier(); } while (0)

__device__ __forceinline__ int hash_v(int v) {
    // v in [0, 64000) -> 12-bit slot. Multiplicative (Knuth) hash, top bits.
    return (int)(((unsigned)v * 2654435761u) >> 20);
}

// Grid = 512 blocks of 1024 threads. Block (r, h) computes row r's softmax,
// dedups the row's tokens that fall in its half of the vocab via a small LDS
// hash map (NOT a vocab-sized table), then writes its 256 KB half-row of w_a
// in ONE uninterrupted fill-style loop:
//   - 64000-bit LDS bitmap marks present slots
//   - stream loop: per 4 slots, test a bitmap nibble; all-absent (~94%) ->
//     store zeros; present -> probe hash for the float weight
// Only 3 barriers in the whole kernel, all before the stream. The w_a store
// stream is never interrupted by barriers/LDS-table lifecycle -> store pipe
// duty cycle ~100% (the fill kernel proves ~26 GB/s/CU needs only that).
//
// Dedup (last-write-wins): pass1 CAS-insert key + atomicMax(val, position);
// pass2 the winner (val==idx) overwrites val with its float weight bits
// (weights >= ~1e-38 -> bits >= ~0x2..e6 >> 2047, so losers can't match).
__global__ __launch_bounds__(1024, 4)
void softmax_scatter_hash(const float* __restrict__ w_es,
                          const int*   __restrict__ x,
                          float* __restrict__ w_a,     // [BATCH, VOCAB]
                          float* __restrict__ w_out)   // [BATCH, SEQ]
{
    __shared__ int      key[HSLOT];        // 16 KB: token local idx, -1 empty
    __shared__ int      val[HSLOT];        // 16 KB: pass1 max pos; pass2 w bits
    __shared__ unsigned bm[HALF / 32];     // 8 KB: presence bitmap
    __shared__ float    red[32];           // reduction scratch

    const int bid = blockIdx.x;
    // XCD swizzle: both halves of row r share bid%8 -> same XCD L2.
    const int r = bid & (BATCH - 1);
    const int h = bid >> 8;                // 0 or 1
    const int t = threadIdx.x;             // 0..1023
    const int lane = t & 63;
    const int wid  = t >> 6;

    // ---- init hash + bitmap (one v4i per thread for key/val) ----
    {
        const v4i m1 = (v4i)(-1);
        ((v4i*)key)[t] = m1;
        ((v4i*)val)[t] = m1;
        if (t < (HALF / 32 / 4)) ((v4i*)bm)[t] = (v4i)(0);
    }

    // ---- load scores + tokens (full row; 2 per thread) ----
    const v2f a  = ((const v2f*)(w_es + (size_t)r * SEQ))[t];
    const v2i xv = ((const v2i*)(x    + (size_t)r * SEQ))[t];

    // ---- block max ----
    float m = fmaxf(a.x, a.y);
    #pragma unroll
    for (int off = 32; off > 0; off >>= 1)
        m = fmaxf(m, __shfl_down(m, off, 64));
    if (lane == 0) red[wid] = m;
    __syncthreads();                       // barrier A: init + max partials
    m = red[0];
    #pragma unroll
    for (int k = 1; k < 16; ++k) m = fmaxf(m, red[k]);

    // ---- pass 1: insert this half's tokens (init is visible after A) ----
    const int i0 = 2 * t;
    const int i1 = 2 * t + 1;
    const int v0 = xv.x - h * HALF;
    const int v1 = xv.y - h * HALF;
    const bool in0 = (unsigned)v0 < (unsigned)HALF;
    const bool in1 = (unsigned)v1 < (unsigned)HALF;

    if (in0) {
        atomicOr(&bm[v0 >> 5], 1u << (v0 & 31));
        int s = hash_v(v0);
        while (true) {
            int k = atomicCAS(&key[s], -1, v0);
            if (k == -1 || k == v0) break;
            s = (s + 1) & (HSLOT - 1);
        }
        atomicMax(&val[s], i0);
    }
    if (in1) {
        atomicOr(&bm[v1 >> 5], 1u << (v1 & 31));
        int s = hash_v(v1);
        while (true) {
            int k = atomicCAS(&key[s], -1, v1);
            if (k == -1 || k == v1) break;
            s = (s + 1) & (HSLOT - 1);
        }
        atomicMax(&val[s], i1);
    }

    // ---- exp + block sum (its syncthreads also drains pass-1 atomics) ----
    const float e0 = __expf(a.x - m);
    const float e1 = __expf(a.y - m);
    float s = e0 + e1;
    #pragma unroll
    for (int off = 32; off > 0; off >>= 1)
        s += __shfl_down(s, off, 64);
    if (lane == 0) red[16 + wid] = s;
    __syncthreads();                       // barrier B: sums + pass-1 done
    s = red[16];
    #pragma unroll
    for (int k = 1; k < 16; ++k) s += red[16 + k];

    const float inv = 1.0f / s;
    const float w0 = e0 * inv;
    const float w1 = e1 * inv;

    // ---- h==0 blocks write the weights output ----
    if (h == 0) {
        v2f wv; wv.x = w0; wv.y = w1;
        ((v2f*)(w_out + (size_t)r * SEQ))[t] = wv;
    }

    // ---- pass 2: winner overwrites val[slot] with float weight bits ----
    if (in0) {
        int sl = hash_v(v0);
        while (key[sl] != v0) sl = (sl + 1) & (HSLOT - 1);
        if (val[sl] == i0) val[sl] = __float_as_int(w0);
    }
    if (in1) {
        int sl = hash_v(v1);
        while (key[sl] != v1) sl = (sl + 1) & (HSLOT - 1);
        if (val[sl] == i1) val[sl] = __float_as_int(w1);
    }
    LBAR();                                // barrier C: weights in place

    // ---- the stream: one barrier-free fill-style loop over 256 KB ----
    float* gp = w_a + (size_t)r * VOCAB + h * HALF;
    for (int g = t; g < (HALF >> 2); g += 1024) {   // 15-16 iters/thread
        const unsigned word = bm[g >> 3];           // 8 lanes share a word
        const unsigned nib  = (word >> ((g & 7) << 2)) & 0xFu;
        v4f o = (v4f)(0.0f);
        if (nib) {
            #pragma unroll
            for (int k = 0; k < 4; ++k) {
                if (nib & (1u << k)) {
                    const int v = (g << 2) + k;
                    int sl = hash_v(v);
                    while (key[sl] != v) sl = (sl + 1) & (HSLOT - 1);
                    o[k] = __int_as_float(val[sl]);
                }
            }
        }
        ((v4f*)gp)[g] = o;
    }
}

extern "C" void kernel_launch(void* const* d_in, const int* in_sizes, int n_in,
                              void* d_out, int out_size, void* d_ws, size_t ws_size,
                              hipStream_t stream) {
    const float* w_es = (const float*)d_in[0];
    const int*   x    = (const int*)d_in[1];

    float* out  = (float*)d_out;
    float* w_a  = out;                          // [256, 128000]
    float* w    = out + (size_t)BATCH * VOCAB;  // [256, 2048]

    softmax_scatter_hash<<<2 * BATCH, 1024, 0, stream>>>(w_es, x, w_a, w);
}

// Round 5
// 138.223 us; speedup vs baseline: 1.0001x; 1.0001x over previous
//
#include <hip/hip_runtime.h>

// Problem constants (from reference setup_inputs)
#define BATCH 256
#define SEQ   2048
#define VOCAB 128000
#define HALF  64000              // vocab slots owned per block
#define HSLOT 4096               // hash slots; distinct tokens/row <= 2048 < 4096

typedef float v4f __attribute__((ext_vector_type(4)));
typedef int   v4i __attribute__((ext_vector_type(4)));
typedef float v2f __attribute__((ext_vector_type(2)));
typedef int   v2i __attribute__((ext_vector_type(2)));

// lgkm-only barrier (m201-verified pattern): orders LDS across the block
// WITHOUT draining outstanding global stores -> the zero-stream stays in
// flight through the softmax reductions.
#define LBAR() do { asm volatile("s_waitcnt lgkmcnt(0)" ::: "memory"); \
                    __builtin_amdgcn_s_barrier(); } while (0)

__device__ __forceinline__ int hash_v(int v) {
    // v in [0, 64000) -> 12-bit slot. Multiplicative (Knuth) hash, top bits.
    return (int)(((unsigned)v * 2654435761u) >> 20);
}

// Grid = 512 blocks of 1024 threads; block (r, h) owns w_a[r, h*HALF ...].
//
// Phase plan (the point: the 133 MB mandatory write is a pure fill-clone):
//   1. load my 2 scores + 2 tokens; init hash
//   2. __syncthreads (publishes init; NO stores outstanding yet -> cheap)
//   3. zero-stream the whole owned 256 KB: unconditional dwordx4, no LDS
//      dependence, fire-and-forget  <-- structurally identical to the
//      6.7 TB/s fill kernel
//   4. softmax (shfl + lgkm-only cross-wave reduce) and hash dedup pass
//      (CAS-insert key, atomicMax position) run WHILE the zeros drain
//   5. one full __syncthreads: vmcnt(0) -> zeros complete; atomics visible
//   6. sparse scatter: each in-range token holder probes the hash; the
//      position-max winner stores its weight directly to global
//      (~1000 scattered dwords per block; last write wins over the zeros
//      by the ordering established in 5)
__global__ __launch_bounds__(1024, 4)
void softmax_zero_then_scatter(const float* __restrict__ w_es,
                               const int*   __restrict__ x,
                               float* __restrict__ w_a,     // [BATCH, VOCAB]
                               float* __restrict__ w_out)   // [BATCH, SEQ]
{
    __shared__ int   key[HSLOT];       // 16 KB: token local idx, -1 empty
    __shared__ int   val[HSLOT];       // 16 KB: max position idx
    __shared__ float red[32];          // cross-wave reduction scratch

    const int bid = blockIdx.x;
    // XCD swizzle: both halves of row r share bid%8 -> same XCD L2.
    const int r = bid & (BATCH - 1);
    const int h = bid >> 8;            // 0 or 1
    const int t = threadIdx.x;         // 0..1023
    const int lane = t & 63;
    const int wid  = t >> 6;           // 0..15

    // ---- 1. inputs (issued before any store) + hash init ----
    const v2f a  = ((const v2f*)(w_es + (size_t)r * SEQ))[t];
    const v2i xv = ((const v2i*)(x    + (size_t)r * SEQ))[t];

    ((v4i*)key)[t] = (v4i)(-1);
    ((v4i*)val)[t] = (v4i)(-1);

    // ---- 2. publish init; drains only the 4 input loads ----
    __syncthreads();

    // ---- 3. zero-stream: fill-clone over the owned 256 KB ----
    v4f* gp4 = (v4f*)(w_a + (size_t)r * VOCAB + h * HALF);
    {
        const v4f z = (v4f)(0.0f);
        #pragma unroll
        for (int j = 0; j < 15; ++j)            // 15*1024 = 15360 groups
            gp4[j * 1024 + t] = z;
        if (t < 640)                            // tail: 16000 - 15360
            gp4[15 * 1024 + t] = z;
    }

    // ---- 4a. softmax while zeros drain (lgkm-only barriers) ----
    float m = fmaxf(a.x, a.y);
    #pragma unroll
    for (int off = 32; off > 0; off >>= 1)
        m = fmaxf(m, __shfl_down(m, off, 64));
    if (lane == 0) red[wid] = m;
    LBAR();
    m = red[0];
    #pragma unroll
    for (int k = 1; k < 16; ++k) m = fmaxf(m, red[k]);

    const float e0 = __expf(a.x - m);
    const float e1 = __expf(a.y - m);
    float s = e0 + e1;
    #pragma unroll
    for (int off = 32; off > 0; off >>= 1)
        s += __shfl_down(s, off, 64);
    if (lane == 0) red[16 + wid] = s;
    LBAR();
    s = red[16];
    #pragma unroll
    for (int k = 1; k < 16; ++k) s += red[16 + k];

    const float inv = 1.0f / s;
    const float w0 = e0 * inv;
    const float w1 = e1 * inv;

    // weights output (h==0): joins the in-flight store stream
    if (h == 0) {
        v2f wv; wv.x = w0; wv.y = w1;
        ((v2f*)(w_out + (size_t)r * SEQ))[t] = wv;
    }

    // ---- 4b. hash dedup pass: CAS-insert key, atomicMax position ----
    const int i0 = 2 * t;
    const int i1 = 2 * t + 1;
    const int v0 = xv.x - h * HALF;
    const int v1 = xv.y - h * HALF;
    const bool in0 = (unsigned)v0 < (unsigned)HALF;
    const bool in1 = (unsigned)v1 < (unsigned)HALF;

    if (in0) {
        int sl = hash_v(v0);
        while (true) {
            int k = atomicCAS(&key[sl], -1, v0);
            if (k == -1 || k == v0) break;
            sl = (sl + 1) & (HSLOT - 1);
        }
        atomicMax(&val[sl], i0);
    }
    if (in1) {
        int sl = hash_v(v1);
        while (true) {
            int k = atomicCAS(&key[sl], -1, v1);
            if (k == -1 || k == v1) break;
            sl = (sl + 1) & (HSLOT - 1);
        }
        atomicMax(&val[sl], i1);
    }

    // ---- 5. ordering point: zeros complete (vmcnt 0), atomics visible ----
    __syncthreads();

    // ---- 6. sparse winner scatter (last write wins over the zeros) ----
    float* gp = w_a + (size_t)r * VOCAB + h * HALF;
    if (in0) {
        int sl = hash_v(v0);
        while (key[sl] != v0) sl = (sl + 1) & (HSLOT - 1);
        if (val[sl] == i0) gp[v0] = w0;
    }
    if (in1) {
        int sl = hash_v(v1);
        while (key[sl] != v1) sl = (sl + 1) & (HSLOT - 1);
        if (val[sl] == i1) gp[v1] = w1;
    }
}

extern "C" void kernel_launch(void* const* d_in, const int* in_sizes, int n_in,
                              void* d_out, int out_size, void* d_ws, size_t ws_size,
                              hipStream_t stream) {
    const float* w_es = (const float*)d_in[0];
    const int*   x    = (const int*)d_in[1];

    float* out  = (float*)d_out;
    float* w_a  = out;                          // [256, 128000]
    float* w    = out + (size_t)BATCH * VOCAB;  // [256, 2048]

    softmax_zero_then_scatter<<<2 * BATCH, 1024, 0, stream>>>(w_es, x, w_a, w);
}